// Round 2
// baseline (21.152 us; speedup 1.0000x reference)
//
#include <hip/hip_runtime.h>

// TaylorLayer: B=262144, n=8, q=1, exp_order=2 -> monomials deg 1..3, T=164, NOUT=8.
//
// Ordering (matches reference recursion):
//   t in [0,8):    x_j
//   t in [8,44):   x_j*x_k, j<=k, j-major
//   t in [44,164): x_j*x_a*x_b, j<=a<=b (j-major, then a, then b)
//
// R2 change: W staged TRANSPOSED in LDS (wt[t][o]) so each monomial t feeds
// 8 FMAs from two broadcast ds_read_b128 (same addr across lanes -> no
// conflict, DS pipe overlaps VALU). Avoids 1312 per-thread global W loads
// whose latency dominated R1 (19.9us vs ~5us VALU floor).

static constexpr int NOUT = 8;
static constexpr int TEXP = 164;

__device__ __forceinline__ float relu(float v) { return fmaxf(v, 0.0f); }

__global__ __launch_bounds__(256) void taylor_kernel(
    const float* __restrict__ x, const float* __restrict__ W,
    const float* __restrict__ b, float* __restrict__ out, int n) {
  __shared__ __align__(16) float wt[TEXP * NOUT];  // wt[t*8+o] = W[o*164+t]

  for (int idx = threadIdx.x; idx < TEXP * NOUT; idx += blockDim.x) {
    int t = idx >> 3, o = idx & 7;
    wt[idx] = W[o * TEXP + t];
  }
  __syncthreads();

  int i = blockIdx.x * blockDim.x + threadIdx.x;
  if (i >= n) return;

  float4 xa = reinterpret_cast<const float4*>(x)[i * 2 + 0];
  float4 xb = reinterpret_cast<const float4*>(x)[i * 2 + 1];
  float xv[8] = {xa.x, xa.y, xa.z, xa.w, xb.x, xb.y, xb.z, xb.w};

  float acc[NOUT];
  {
    float4 b0 = reinterpret_cast<const float4*>(b)[0];
    float4 b1 = reinterpret_cast<const float4*>(b)[1];
    acc[0] = b0.x; acc[1] = b0.y; acc[2] = b0.z; acc[3] = b0.w;
    acc[4] = b1.x; acc[5] = b1.y; acc[6] = b1.z; acc[7] = b1.w;
  }

  // 8 FMAs for monomial t (compile-time t -> ds_read_b128 with imm offsets)
  auto fma8 = [&](int t, float m) {
    float4 wa = reinterpret_cast<const float4*>(wt)[t * 2 + 0];
    float4 wb = reinterpret_cast<const float4*>(wt)[t * 2 + 1];
    acc[0] = fmaf(wa.x, m, acc[0]);
    acc[1] = fmaf(wa.y, m, acc[1]);
    acc[2] = fmaf(wa.z, m, acc[2]);
    acc[3] = fmaf(wa.w, m, acc[3]);
    acc[4] = fmaf(wb.x, m, acc[4]);
    acc[5] = fmaf(wb.y, m, acc[5]);
    acc[6] = fmaf(wb.z, m, acc[6]);
    acc[7] = fmaf(wb.w, m, acc[7]);
  };

  int t = 0;

  // ---- degree 1 ----
#pragma unroll
  for (int j = 0; j < 8; ++j) {
    fma8(t, xv[j]);
    ++t;
  }

  // ---- degree 2 (cache for degree 3) ----
  float d2[36];
  int p = 0;
#pragma unroll
  for (int j = 0; j < 8; ++j) {
#pragma unroll
    for (int k = j; k < 8; ++k) {
      float m = xv[j] * xv[k];
      d2[p] = m;
      ++p;
      fma8(t, m);
      ++t;
    }
  }

  // ---- degree 3: x_j * d2[(a,b)] for j<=a<=b ----
#pragma unroll
  for (int j = 0; j < 8; ++j) {
#pragma unroll
    for (int a = j; a < 8; ++a) {
      int rowstart = a * 8 - a * (a - 1) / 2 - a;  // idx2(a,b) = rowstart + b
#pragma unroll
      for (int bb = a; bb < 8; ++bb) {
        float m = xv[j] * d2[rowstart + bb];
        fma8(t, m);
        ++t;
      }
    }
  }

  float4 o0 = make_float4(relu(acc[0]), relu(acc[1]), relu(acc[2]), relu(acc[3]));
  float4 o1 = make_float4(relu(acc[4]), relu(acc[5]), relu(acc[6]), relu(acc[7]));
  reinterpret_cast<float4*>(out)[i * 2 + 0] = o0;
  reinterpret_cast<float4*>(out)[i * 2 + 1] = o1;
}

extern "C" void kernel_launch(void* const* d_in, const int* in_sizes, int n_in,
                              void* d_out, int out_size, void* d_ws, size_t ws_size,
                              hipStream_t stream) {
  const float* x = (const float*)d_in[0];   // [262144, 8, 1]
  const float* W = (const float*)d_in[1];   // [8, 164]
  const float* b = (const float*)d_in[2];   // [8, 1]
  float* out = (float*)d_out;               // [262144, 8, 1]

  int n = in_sizes[0] / 8;  // batch elements
  int block = 256;
  int grid = (n + block - 1) / block;
  taylor_kernel<<<grid, block, 0, stream>>>(x, W, b, out, n);
}

// Round 3
// 17.642 us; speedup vs baseline: 1.1990x; 1.1990x over previous
//
#include <hip/hip_runtime.h>
#include <hip/hip_bf16.h>
#include <string.h>

// TaylorLayer via MFMA: out[B,8] = relu(W[8,164] @ epd[164,B] + b)
// epd = monomials deg 1..3 of x[8] in the reference's recursion order.
//
// R3: contraction moved to matrix pipe (mfma_f32_32x32x16_bf16).
//  - R1 (per-lane global W) and R2 (LDS-broadcast W) both ~20us: every W
//    value was re-fetched per 64 elements and feeds exactly 1 FMA ->
//    VMEM/DS pipe bound (R2: 328 ds_read_b128 x 16 waves x ~12cyc = 63K
//    cyc/CU = 26us). MFMA removes per-monomial W traffic entirely.
//  - W is PERMUTED into A-fragment slot order (prep kernel -> d_ws, bf16),
//    making correctness independent of the exact within-lane k-map (A/B
//    maps are symmetric on CDNA).
//  - Each lane: computes all 164 monomials (fp32) of element lane&31,
//    selects its k-half (hi = lane>=32) per slot via cndmask, cvt to bf16,
//    11 MFMAs over K=176 (12 pad slots are zero on both sides).
//  - C/D layout (verified m74/m101): col=lane&31, row=(reg&3)+8*(reg>>2)
//    +4*(lane>>5) -> regs 0..3 = out rows 4h+0..3 -> float4 store.

static constexpr int TEXP = 164;
static constexpr int NOUT = 8;
static constexpr int NMFMA = 11;   // K = 176
static constexpr int HALF = 88;    // monomial slots per k-half

using f32x16 = __attribute__((ext_vector_type(16))) float;
using short8 = __attribute__((ext_vector_type(8))) short;

// ---- compile-time monomial index math (reference t-order) ----
// t in [0,8):   x_j
// t in [8,44):  d2[p], p = idx2(j,k) j<=k j-major
// t in [44,164): x_j * d2[idx2(a,b)], j<=a<=b, j-major then a then b
constexpr int rowstart2(int j) { return j * 8 - j * (j - 1) / 2; }
constexpr int start3(int j) {
  int s = 44;
  for (int jp = 0; jp < j; ++jp) s += (8 - jp) * (9 - jp) / 2;
  return s;
}
struct D3 { int j, p; };
constexpr D3 d3idx(int M) {
  int j = 0;
  while (start3(j + 1) <= M) ++j;
  int q = M - start3(j);
  int a = j;
  while (q >= (8 - a)) { q -= (8 - a); ++a; }
  int b = a + q;
  return { j, rowstart2(a) + (b - a) };
}

template <int M>
__device__ __forceinline__ float mono(const float (&xv)[8], const float (&d2)[36]) {
  if constexpr (M < 8) {
    return xv[M];
  } else if constexpr (M < 44) {
    return d2[M - 8];
  } else {
    constexpr D3 t = d3idx(M);
    return xv[t.j] * d2[t.p];
  }
}

__device__ __forceinline__ short bf16bits(float v) {
  __hip_bfloat16 h = __float2bfloat16(v);  // RNE; compiler lowers to v_cvt
  short s;
  memcpy(&s, &h, 2);
  return s;
}

template <int C>
__device__ __forceinline__ void do_slot(const float (&xv)[8], const float (&d2)[36],
                                        bool hi, short8& bv) {
  float v0 = mono<C>(xv, d2);
  float v1;
  if constexpr (HALF + C < TEXP) v1 = mono<HALF + C>(xv, d2);
  else v1 = 0.0f;
  float v = hi ? v1 : v0;   // per-lane cndmask
  bv[C & 7] = bf16bits(v);
}

template <int I>
__device__ __forceinline__ void slot8(const float (&xv)[8], const float (&d2)[36],
                                      bool hi, short8& bv) {
  do_slot<8 * I + 0>(xv, d2, hi, bv);
  do_slot<8 * I + 1>(xv, d2, hi, bv);
  do_slot<8 * I + 2>(xv, d2, hi, bv);
  do_slot<8 * I + 3>(xv, d2, hi, bv);
  do_slot<8 * I + 4>(xv, d2, hi, bv);
  do_slot<8 * I + 5>(xv, d2, hi, bv);
  do_slot<8 * I + 6>(xv, d2, hi, bv);
  do_slot<8 * I + 7>(xv, d2, hi, bv);
}

template <int I>
struct MfmaStep {
  static __device__ __forceinline__ void run(const float (&xv)[8], const float (&d2)[36],
                                             bool hi, const short8 (&af)[NMFMA],
                                             f32x16& acc) {
    short8 bv;
    slot8<I>(xv, d2, hi, bv);
    acc = __builtin_amdgcn_mfma_f32_32x32x16_bf16(af[I], bv, acc, 0, 0, 0);
    MfmaStep<I + 1>::run(xv, d2, hi, af, acc);
  }
};
template <>
struct MfmaStep<NMFMA> {
  static __device__ __forceinline__ void run(const float (&)[8], const float (&)[36],
                                             bool, const short8 (&)[NMFMA], f32x16&) {}
};

// ---- prep: Wperm bf16 in A-frag slot order: wp[(i*64+lane)*8 + j] =
//      bf16( W[row][88h + 8i + j] ), row=lane&31, h=lane>>5 (0 if OOB) ----
__global__ void prep_w(const float* __restrict__ W, unsigned short* __restrict__ wp) {
  for (int idx = threadIdx.x + blockIdx.x * blockDim.x; idx < NMFMA * 64 * 8;
       idx += blockDim.x * gridDim.x) {
    int j = idx & 7;
    int lane = (idx >> 3) & 63;
    int i = idx >> 9;
    int row = lane & 31, h = lane >> 5;
    int m = HALF * h + 8 * i + j;
    float v = (row < NOUT && m < TEXP) ? W[row * TEXP + m] : 0.0f;
    union { float f; unsigned int u; } c; c.f = v;
    unsigned int u = c.u;
    wp[idx] = (unsigned short)((u + 0x7fffu + ((u >> 16) & 1u)) >> 16);  // RNE
  }
}

__global__ __launch_bounds__(256) void taylor_mfma(
    const float* __restrict__ x, const float* __restrict__ b,
    const unsigned short* __restrict__ wp, float* __restrict__ out, int ngroups) {
  const int lane = (int)(threadIdx.x & 63);
  const bool hi = lane >= 32;
  const int col = lane & 31;
  const int h4 = hi ? 4 : 0;

  // A fragments (Wperm), hoisted: 11 x 16B, L1-hot
  short8 afrag[NMFMA];
#pragma unroll
  for (int i = 0; i < NMFMA; ++i)
    afrag[i] = *reinterpret_cast<const short8*>(wp + (i * 64 + lane) * 8);

  const float4 bv4 = *reinterpret_cast<const float4*>(b + h4);

  const int wave = (int)((blockIdx.x * blockDim.x + threadIdx.x) >> 6);
  const int nw = (int)((gridDim.x * blockDim.x) >> 6);

  for (int g = wave; g < ngroups; g += nw) {
    const int elem = g * 32 + col;
    float4 xa = reinterpret_cast<const float4*>(x)[elem * 2 + 0];
    float4 xb = reinterpret_cast<const float4*>(x)[elem * 2 + 1];
    float xv[8] = {xa.x, xa.y, xa.z, xa.w, xb.x, xb.y, xb.z, xb.w};

    float d2[36];
#pragma unroll
    for (int j = 0; j < 8; ++j) {
#pragma unroll
      for (int k = j; k < 8; ++k) {
        d2[rowstart2(j) + (k - j)] = xv[j] * xv[k];
      }
    }

    f32x16 acc;
#pragma unroll
    for (int r = 0; r < 16; ++r) acc[r] = 0.0f;

    MfmaStep<0>::run(xv, d2, hi, afrag, acc);

    float4 o;
    o.x = fmaxf(acc[0] + bv4.x, 0.0f);
    o.y = fmaxf(acc[1] + bv4.y, 0.0f);
    o.z = fmaxf(acc[2] + bv4.z, 0.0f);
    o.w = fmaxf(acc[3] + bv4.w, 0.0f);
    reinterpret_cast<float4*>(out)[elem * 2 + (hi ? 1 : 0)] = o;
  }
}

extern "C" void kernel_launch(void* const* d_in, const int* in_sizes, int n_in,
                              void* d_out, int out_size, void* d_ws, size_t ws_size,
                              hipStream_t stream) {
  const float* x = (const float*)d_in[0];   // [262144, 8, 1]
  const float* W = (const float*)d_in[1];   // [8, 164]
  const float* b = (const float*)d_in[2];   // [8, 1]
  float* out = (float*)d_out;               // [262144, 8]
  unsigned short* wp = (unsigned short*)d_ws;  // 11*64*8 bf16 = 11264 B

  int n = in_sizes[0] / 8;       // batch elements
  int ngroups = n / 32;          // 32 elements per wave-group

  prep_w<<<8, 256, 0, stream>>>(W, wp);
  taylor_mfma<<<1024, 256, 0, stream>>>(x, b, wp, out, ngroups);
}